// Round 7
// baseline (401.890 us; speedup 1.0000x reference)
//
#include <hip/hip_runtime.h>

#define NN 50000
#define CC 128
#define EE 800000
#define NT 1563          // ceil(NN/32)
#define NBLK 196         // ceil(NN/256)

typedef short bf16x8 __attribute__((ext_vector_type(8)));
typedef float f32x4 __attribute__((ext_vector_type(4)));

__device__ __forceinline__ float bf2f(unsigned int u16) {
  union { unsigned int u; float f; } x; x.u = u16 << 16; return x.f;
}
__device__ __forceinline__ unsigned short f2bf(float f) {
  union { float f; unsigned int u; } x; x.f = f;
  unsigned int u = x.u;
  unsigned int r = (u + 0x7fffu + ((u >> 16) & 1u)) >> 16;
  return (unsigned short)r;
}
__device__ __forceinline__ float fsigmoid(float x) {
  return __fdividef(1.f, 1.f + __expf(-x));
}
__device__ __forceinline__ float ftanh(float x) {
  return 1.f - __fdividef(2.f, 1.f + __expf(2.f * x));
}

// ---------------- casts ----------------
__global__ void cast_f2b_k(const float* __restrict__ in, unsigned short* __restrict__ out, int n4) {
  int i = blockIdx.x * blockDim.x + threadIdx.x;
  int stride = gridDim.x * blockDim.x;
  for (; i < n4; i += stride) {
    float4 v = ((const float4*)in)[i];
    ushort4 o;
    o.x = f2bf(v.x); o.y = f2bf(v.y); o.z = f2bf(v.z); o.w = f2bf(v.w);
    ((ushort4*)out)[i] = o;
  }
}

// blocks 0-191: W_c = W_ih @ W_lin (384x128) fp32->bf16; blocks 192-239: cast Whh
__global__ __launch_bounds__(256) void wprep_k(const float* __restrict__ Wih,
                                               const float* __restrict__ Wlin,
                                               const float* __restrict__ Whh,
                                               unsigned short* __restrict__ Wcb,
                                               unsigned short* __restrict__ Whhb) {
  if (blockIdx.x < 192) {
    int gid = blockIdx.x * 256 + threadIdx.x;   // 49152 = 384*128
    int i = gid >> 7, j = gid & 127;
    float acc = 0.f;
    #pragma unroll 8
    for (int k = 0; k < 128; ++k)
      acc += Wih[i * 128 + k] * Wlin[k * 128 + j];
    Wcb[i * 128 + j] = f2bf(acc);
  } else {
    int i = (blockIdx.x - 192) * 256 + threadIdx.x;   // 12288 float4s
    float4 v = ((const float4*)Whh)[i];
    ushort4 o;
    o.x = f2bf(v.x); o.y = f2bf(v.y); o.z = f2bf(v.z); o.w = f2bf(v.w);
    ((ushort4*)Whhb)[i] = o;
  }
}

__global__ void zero_k(int* __restrict__ p, int n) {
  int i = blockIdx.x * blockDim.x + threadIdx.x;
  if (i < n) p[i] = 0;
}

// ---------------- CSR build ----------------
// 4 edges per thread (E % 4 == 0)
__global__ void hist_k(const int* __restrict__ dst, int* __restrict__ cnt, int n4) {
  int i = blockIdx.x * blockDim.x + threadIdx.x;
  if (i < n4) {
    int4 d = ((const int4*)dst)[i];
    atomicAdd(&cnt[d.x], 1);
    atomicAdd(&cnt[d.y], 1);
    atomicAdd(&cnt[d.z], 1);
    atomicAdd(&cnt[d.w], 1);
  }
}

__global__ __launch_bounds__(256) void scan1_k(const int* __restrict__ cnt,
                                               int* __restrict__ rowptr,
                                               int* __restrict__ bsum, int N) {
  __shared__ int wtot[4];
  int tid = threadIdx.x, lane = tid & 63, w = tid >> 6;
  int i = blockIdx.x * 256 + tid;
  int v = (i < N) ? cnt[i] : 0;
  int x = v;
  #pragma unroll
  for (int off = 1; off < 64; off <<= 1) {
    int t = __shfl_up(x, off, 64);
    if (lane >= off) x += t;
  }
  if (lane == 63) wtot[w] = x;
  __syncthreads();
  int woff = 0;
  for (int j = 0; j < w; ++j) woff += wtot[j];
  int excl = x - v + woff;
  if (i < N) rowptr[i] = excl;
  if (tid == 255) bsum[blockIdx.x] = excl + v;
}

__global__ __launch_bounds__(256) void scan2_k(int* __restrict__ bsum, int* __restrict__ rowptr, int NB) {
  __shared__ int wtot[4];
  int tid = threadIdx.x, lane = tid & 63, w = tid >> 6;
  int v = (tid < NB) ? bsum[tid] : 0;
  int x = v;
  #pragma unroll
  for (int off = 1; off < 64; off <<= 1) {
    int t = __shfl_up(x, off, 64);
    if (lane >= off) x += t;
  }
  if (lane == 63) wtot[w] = x;
  __syncthreads();
  int woff = 0;
  for (int j = 0; j < w; ++j) woff += wtot[j];
  int excl = x - v + woff;
  if (tid < NB) bsum[tid] = excl;
  if (tid == 255) rowptr[NN] = excl + v;
}

__global__ void scan3_k(int* __restrict__ rowptr, const int* __restrict__ bsum,
                        int* __restrict__ cursor, int N) {
  int i = blockIdx.x * 256 + threadIdx.x;
  if (i < N) {
    int r = rowptr[i] + bsum[i >> 8];
    rowptr[i] = r;
    cursor[i] = r;
  }
}

// 4 edges per thread; colx written via atomicExch (TCC-side, avoids 64B write-allocate per 4B)
__global__ void fill_k(const int* __restrict__ src, const int* __restrict__ dst,
                       int* __restrict__ cursor, int* __restrict__ colx, int n4) {
  int i = blockIdx.x * blockDim.x + threadIdx.x;
  if (i < n4) {
    int4 s = ((const int4*)src)[i];
    int4 d = ((const int4*)dst)[i];
    int p0 = atomicAdd(&cursor[d.x], 1);
    int p1 = atomicAdd(&cursor[d.y], 1);
    int p2 = atomicAdd(&cursor[d.z], 1);
    int p3 = atomicAdd(&cursor[d.w], 1);
    atomicExch(&colx[p0], s.x);
    atomicExch(&colx[p1], s.y);
    atomicExch(&colx[p2], s.z);
    atomicExch(&colx[p3], s.w);
  }
}

// ---------------- aggregated_state = segment_sum(state[src], dst) ----------------
// wave per dst row; lanes 0-31 / 32-63 process interleaved edges (8 rows in flight)
__global__ __launch_bounds__(256) void agg2_k(const unsigned short* __restrict__ M,
                                              const int* __restrict__ rowptr,
                                              const int* __restrict__ colx,
                                              unsigned short* __restrict__ P, int N) {
  int wid = (blockIdx.x * 256 + threadIdx.x) >> 6;
  int lane = threadIdx.x & 63;
  if (wid >= N) return;
  int beg = rowptr[wid], end = rowptr[wid + 1];
  int half = lane >> 5, li = lane & 31;
  float a0 = 0.f, a1 = 0.f, a2 = 0.f, a3 = 0.f;
  int n = end - beg;
  int i = 0;
  for (; i + 8 <= n; i += 8) {
    int e = beg + i + half;
    int s0 = colx[e], s1 = colx[e + 2], s2 = colx[e + 4], s3 = colx[e + 6];
    uint2 v0 = *(const uint2*)(M + s0 * CC + li * 4);
    uint2 v1 = *(const uint2*)(M + s1 * CC + li * 4);
    uint2 v2 = *(const uint2*)(M + s2 * CC + li * 4);
    uint2 v3 = *(const uint2*)(M + s3 * CC + li * 4);
    a0 += bf2f(v0.x & 0xffffu); a1 += bf2f(v0.x >> 16); a2 += bf2f(v0.y & 0xffffu); a3 += bf2f(v0.y >> 16);
    a0 += bf2f(v1.x & 0xffffu); a1 += bf2f(v1.x >> 16); a2 += bf2f(v1.y & 0xffffu); a3 += bf2f(v1.y >> 16);
    a0 += bf2f(v2.x & 0xffffu); a1 += bf2f(v2.x >> 16); a2 += bf2f(v2.y & 0xffffu); a3 += bf2f(v2.y >> 16);
    a0 += bf2f(v3.x & 0xffffu); a1 += bf2f(v3.x >> 16); a2 += bf2f(v3.y & 0xffffu); a3 += bf2f(v3.y >> 16);
  }
  for (; i + 2 <= n; i += 2) {
    int e = beg + i + half;
    int s = colx[e];
    uint2 v = *(const uint2*)(M + s * CC + li * 4);
    a0 += bf2f(v.x & 0xffffu); a1 += bf2f(v.x >> 16); a2 += bf2f(v.y & 0xffffu); a3 += bf2f(v.y >> 16);
  }
  if (i < n && half == 0) {
    int s = colx[beg + i];
    uint2 v = *(const uint2*)(M + s * CC + li * 4);
    a0 += bf2f(v.x & 0xffffu); a1 += bf2f(v.x >> 16); a2 += bf2f(v.y & 0xffffu); a3 += bf2f(v.y >> 16);
  }
  a0 += __shfl_xor(a0, 32, 64);
  a1 += __shfl_xor(a1, 32, 64);
  a2 += __shfl_xor(a2, 32, 64);
  a3 += __shfl_xor(a3, 32, 64);
  if (half == 0) {
    uint2 o;
    o.x = (unsigned int)f2bf(a0) | ((unsigned int)f2bf(a1) << 16);
    o.y = (unsigned int)f2bf(a2) | ((unsigned int)f2bf(a3) << 16);
    *(uint2*)(P + wid * CC + li * 4) = o;
  }
}

// ---------------- fused gate GEMMs + GRU elementwise (weights in VGPRs) ----------------
// grid = 512: blockIdx&1 = column half (64 gate-cols), blockIdx>>1 = row group (stride 256)
__global__ __launch_bounds__(256, 2) void gru3_k(const unsigned short* __restrict__ Pb,
                                                 const unsigned short* __restrict__ Sb_in,
                                                 unsigned short* __restrict__ Sb_out,
                                                 const float* __restrict__ h_in,
                                                 float* __restrict__ h_out,
                                                 const unsigned short* __restrict__ Wcb,
                                                 const unsigned short* __restrict__ Whhb,
                                                 const float* __restrict__ bih,
                                                 const float* __restrict__ bhh) {
  __shared__ unsigned short sA[2][2][32][128];   // 32 KB: [buf][mat 0=agg 1=state]
  const int tid = threadIdx.x;
  const int half = blockIdx.x & 1;
  const int group = blockIdx.x >> 1;
  const int lane = tid & 63, w = tid >> 6;
  const int l15 = lane & 15, l4 = lane >> 4;

  const int c_loc = w * 16 + l15;
  const int cg = half * 64 + c_loc;

  // B fragments in registers: 6 panels x 4 k-steps x bf16x8 = 96 VGPR/lane.
  bf16x8 Breg[6][4];
  #pragma unroll
  for (int pi = 0; pi < 6; ++pi) {
    const unsigned short* Wm = (pi < 3) ? Wcb : Whhb;
    int p = (pi < 3) ? pi : pi - 3;
    const unsigned short* base = Wm + (p * 128 + cg) * 128 + l4 * 8;
    #pragma unroll
    for (int ks = 0; ks < 4; ++ks)
      Breg[pi][ks] = *(const bf16x8*)(base + ks * 32);
  }

  const float bir = bih[cg], biz = bih[cg + 128], bin_ = bih[cg + 256];
  const float bhr = bhh[cg], bhz = bhh[cg + 128], bhn = bhh[cg + 256];

  auto loadA = [&](int t, uint4* r) {
    int rowbase = t * 32;
    #pragma unroll
    for (int k = 0; k < 4; ++k) {
      int idx = k * 256 + tid;                 // 1024 chunks: [mat][row][ch]
      int mat = idx >> 9, j = idx & 511, row = j >> 4, ch = j & 15;
      int grow = rowbase + row;
      const unsigned short* srcp = mat ? Sb_in : Pb;
      r[k] = (grow < NN) ? *(const uint4*)(srcp + grow * 128 + ch * 8) : make_uint4(0, 0, 0, 0);
    }
  };
  auto writeA = [&](int buf, const uint4* r) {
    #pragma unroll
    for (int k = 0; k < 4; ++k) {
      int idx = k * 256 + tid;
      int mat = idx >> 9, j = idx & 511, row = j >> 4, ch = j & 15;
      *(uint4*)&sA[buf][mat][row][((ch ^ (row & 15)) * 8)] = r[k];
    }
  };

  uint4 pre[4];
  int t0 = group;
  loadA(t0, pre);
  writeA(0, pre);
  int cur = 0;
  for (int t = t0; t < NT; t += 256) {
    __syncthreads();
    int tn = t + 256;
    uint4 nxt[4];
    if (tn < NT) loadA(tn, nxt);

    f32x4 acc[6][2] = {};
    #pragma unroll
    for (int ks = 0; ks < 4; ++ks) {
      bf16x8 a[2][2];
      #pragma unroll
      for (int mat = 0; mat < 2; ++mat)
        #pragma unroll
        for (int rt = 0; rt < 2; ++rt) {
          int row = rt * 16 + l15;
          a[mat][rt] = *(const bf16x8*)&sA[cur][mat][row][(((ks * 4 + l4) ^ l15) * 8)];
        }
      #pragma unroll
      for (int pi = 0; pi < 6; ++pi) {
        int am = (pi < 3) ? 0 : 1;
        acc[pi][0] = __builtin_amdgcn_mfma_f32_16x16x32_bf16(a[am][0], Breg[pi][ks], acc[pi][0], 0, 0, 0);
        acc[pi][1] = __builtin_amdgcn_mfma_f32_16x16x32_bf16(a[am][1], Breg[pi][ks], acc[pi][1], 0, 0, 0);
      }
    }

    int rowbase = t * 32;
    #pragma unroll
    for (int rt = 0; rt < 2; ++rt)
      #pragma unroll
      for (int i = 0; i < 4; ++i) {
        int row = rowbase + rt * 16 + l4 * 4 + i;
        if (row < NN) {
          float gir = acc[0][rt][i] + bir;
          float giz = acc[1][rt][i] + biz;
          float gin = acc[2][rt][i] + bin_;
          float ghr = acc[3][rt][i] + bhr;
          float ghz = acc[4][rt][i] + bhz;
          float ghn = acc[5][rt][i] + bhn;
          float r = fsigmoid(gir + ghr);
          float z = fsigmoid(giz + ghz);
          float n = ftanh(gin + r * ghn);
          float h = h_in[row * 128 + cg];
          float o = n + z * (h - n);
          h_out[row * 128 + cg] = o;
          Sb_out[row * 128 + cg] = f2bf(o);
        }
      }
    if (tn < NT) writeA(cur ^ 1, nxt);
    cur ^= 1;
  }
}

extern "C" void kernel_launch(void* const* d_in, const int* in_sizes, int n_in,
                              void* d_out, int out_size, void* d_ws, size_t ws_size,
                              hipStream_t stream) {
  const float* x    = (const float*)d_in[0];
  const int*   ei   = (const int*)d_in[1];
  const float* Wlin = (const float*)d_in[2];
  const float* Wih  = (const float*)d_in[3];
  const float* Whh  = (const float*)d_in[4];
  const float* bih  = (const float*)d_in[5];
  const float* bhh  = (const float*)d_in[6];
  float* out = (float*)d_out;

  char* ws = (char*)d_ws;
  size_t off = 0;
  auto alloc = [&](size_t bytes) -> void* {
    void* p = ws + off;
    off += (bytes + 255) & ~(size_t)255;
    return p;
  };
  unsigned short* SbA  = (unsigned short*)alloc((size_t)NN * CC * 2);
  unsigned short* SbB  = (unsigned short*)alloc((size_t)NN * CC * 2);
  unsigned short* Prb  = (unsigned short*)alloc((size_t)NN * CC * 2);
  float*          Sf   = (float*)alloc((size_t)NN * CC * 4);
  unsigned short* Wcb  = (unsigned short*)alloc((size_t)3 * CC * CC * 2);
  unsigned short* Whhb = (unsigned short*)alloc((size_t)3 * CC * CC * 2);
  int* rowptr = (int*)alloc((size_t)(NN + 1) * 4);
  int* cursor = (int*)alloc((size_t)NN * 4);
  int* colx   = (int*)alloc((size_t)EE * 4);
  int* bsum   = (int*)alloc(256 * 4);

  const int* srcI = ei;
  const int* dstI = ei + EE;

  cast_f2b_k<<<1024, 256, 0, stream>>>(x, SbA, NN * CC / 4);
  wprep_k<<<240, 256, 0, stream>>>(Wih, Wlin, Whh, Wcb, Whhb);

  zero_k<<<NBLK, 256, 0, stream>>>(cursor, NN);
  hist_k<<<(EE / 4 + 255) / 256, 256, 0, stream>>>(dstI, cursor, EE / 4);
  scan1_k<<<NBLK, 256, 0, stream>>>(cursor, rowptr, bsum, NN);
  scan2_k<<<1, 256, 0, stream>>>(bsum, rowptr, NBLK);
  scan3_k<<<NBLK, 256, 0, stream>>>(rowptr, bsum, cursor, NN);
  fill_k<<<(EE / 4 + 255) / 256, 256, 0, stream>>>(srcI, dstI, cursor, colx, EE / 4);

  const int aggBlocks = (NN + 3) / 4;

  // step 1 (h = x, state = bf16(x))
  agg2_k<<<aggBlocks, 256, 0, stream>>>(SbA, rowptr, colx, Prb, NN);
  gru3_k<<<512, 256, 0, stream>>>(Prb, SbA, SbB, x, Sf, Wcb, Whhb, bih, bhh);
  // step 2
  agg2_k<<<aggBlocks, 256, 0, stream>>>(SbB, rowptr, colx, Prb, NN);
  gru3_k<<<512, 256, 0, stream>>>(Prb, SbB, SbA, Sf, Sf, Wcb, Whhb, bih, bhh);
  // step 3 (final state -> d_out)
  agg2_k<<<aggBlocks, 256, 0, stream>>>(SbA, rowptr, colx, Prb, NN);
  gru3_k<<<512, 256, 0, stream>>>(Prb, SbA, SbB, Sf, out, Wcb, Whhb, bih, bhh);
}

// Round 9
// 344.796 us; speedup vs baseline: 1.1656x; 1.1656x over previous
//
#include <hip/hip_runtime.h>

#define NN 50000
#define CC 128
#define EE 800000
#define NT 1563          // ceil(NN/32)
#define NBLK 196         // ceil(NN/256)

typedef short bf16x8 __attribute__((ext_vector_type(8)));
typedef float f32x4 __attribute__((ext_vector_type(4)));

__device__ __forceinline__ float bf2f(unsigned int u16) {
  union { unsigned int u; float f; } x; x.u = u16 << 16; return x.f;
}
__device__ __forceinline__ unsigned short f2bf(float f) {
  union { float f; unsigned int u; } x; x.f = f;
  unsigned int u = x.u;
  unsigned int r = (u + 0x7fffu + ((u >> 16) & 1u)) >> 16;
  return (unsigned short)r;
}
__device__ __forceinline__ float fsigmoid(float x) {
  return __fdividef(1.f, 1.f + __expf(-x));
}
__device__ __forceinline__ float ftanh(float x) {
  return 1.f - __fdividef(2.f, 1.f + __expf(2.f * x));
}

// ---------------- casts ----------------
__global__ void cast_f2b_k(const float* __restrict__ in, unsigned short* __restrict__ out, int n4) {
  int i = blockIdx.x * blockDim.x + threadIdx.x;
  int stride = gridDim.x * blockDim.x;
  for (; i < n4; i += stride) {
    float4 v = ((const float4*)in)[i];
    ushort4 o;
    o.x = f2bf(v.x); o.y = f2bf(v.y); o.z = f2bf(v.z); o.w = f2bf(v.w);
    ((ushort4*)out)[i] = o;
  }
}

// blocks 0-191: W_c = W_ih @ W_lin (384x128) fp32->bf16; blocks 192-239: cast Whh
__global__ __launch_bounds__(256) void wprep_k(const float* __restrict__ Wih,
                                               const float* __restrict__ Wlin,
                                               const float* __restrict__ Whh,
                                               unsigned short* __restrict__ Wcb,
                                               unsigned short* __restrict__ Whhb) {
  if (blockIdx.x < 192) {
    int gid = blockIdx.x * 256 + threadIdx.x;   // 49152 = 384*128
    int i = gid >> 7, j = gid & 127;
    float acc = 0.f;
    #pragma unroll 8
    for (int k = 0; k < 128; ++k)
      acc += Wih[i * 128 + k] * Wlin[k * 128 + j];
    Wcb[i * 128 + j] = f2bf(acc);
  } else {
    int i = (blockIdx.x - 192) * 256 + threadIdx.x;   // 12288 float4s
    float4 v = ((const float4*)Whh)[i];
    ushort4 o;
    o.x = f2bf(v.x); o.y = f2bf(v.y); o.z = f2bf(v.z); o.w = f2bf(v.w);
    ((ushort4*)Whhb)[i] = o;
  }
}

__global__ void zero_k(int* __restrict__ p, int n) {
  int i = blockIdx.x * blockDim.x + threadIdx.x;
  if (i < n) p[i] = 0;
}

// ---------------- CSR build ----------------
// 4 edges per thread; keep the atomicAdd return as the edge's rank within its dst segment
__global__ void hist_k(const int* __restrict__ dst, int* __restrict__ cnt,
                       int* __restrict__ rank, int n4) {
  int i = blockIdx.x * blockDim.x + threadIdx.x;
  if (i < n4) {
    int4 d = ((const int4*)dst)[i];
    int4 r;
    r.x = atomicAdd(&cnt[d.x], 1);
    r.y = atomicAdd(&cnt[d.y], 1);
    r.z = atomicAdd(&cnt[d.z], 1);
    r.w = atomicAdd(&cnt[d.w], 1);
    ((int4*)rank)[i] = r;
  }
}

__global__ __launch_bounds__(256) void scan1_k(const int* __restrict__ cnt,
                                               int* __restrict__ rowptr,
                                               int* __restrict__ bsum, int N) {
  __shared__ int wtot[4];
  int tid = threadIdx.x, lane = tid & 63, w = tid >> 6;
  int i = blockIdx.x * 256 + tid;
  int v = (i < N) ? cnt[i] : 0;
  int x = v;
  #pragma unroll
  for (int off = 1; off < 64; off <<= 1) {
    int t = __shfl_up(x, off, 64);
    if (lane >= off) x += t;
  }
  if (lane == 63) wtot[w] = x;
  __syncthreads();
  int woff = 0;
  for (int j = 0; j < w; ++j) woff += wtot[j];
  int excl = x - v + woff;
  if (i < N) rowptr[i] = excl;
  if (tid == 255) bsum[blockIdx.x] = excl + v;
}

__global__ __launch_bounds__(256) void scan2_k(int* __restrict__ bsum, int* __restrict__ rowptr, int NB) {
  __shared__ int wtot[4];
  int tid = threadIdx.x, lane = tid & 63, w = tid >> 6;
  int v = (tid < NB) ? bsum[tid] : 0;
  int x = v;
  #pragma unroll
  for (int off = 1; off < 64; off <<= 1) {
    int t = __shfl_up(x, off, 64);
    if (lane >= off) x += t;
  }
  if (lane == 63) wtot[w] = x;
  __syncthreads();
  int woff = 0;
  for (int j = 0; j < w; ++j) woff += wtot[j];
  int excl = x - v + woff;
  if (tid < NB) bsum[tid] = excl;
  if (tid == 255) rowptr[NN] = excl + v;
}

__global__ void scan3_k(int* __restrict__ rowptr, const int* __restrict__ bsum, int N) {
  int i = blockIdx.x * 256 + threadIdx.x;
  if (i < N) rowptr[i] = rowptr[i] + bsum[i >> 8];
}

// atomic-free fill: pos = rowptr[dst] + rank  (plain scatter stores, fully pipelined)
__global__ void fill_k(const int* __restrict__ src, const int* __restrict__ dst,
                       const int* __restrict__ rank, const int* __restrict__ rowptr,
                       int* __restrict__ colx, int n4) {
  int i = blockIdx.x * blockDim.x + threadIdx.x;
  if (i < n4) {
    int4 s = ((const int4*)src)[i];
    int4 d = ((const int4*)dst)[i];
    int4 r = ((const int4*)rank)[i];
    colx[rowptr[d.x] + r.x] = s.x;
    colx[rowptr[d.y] + r.y] = s.y;
    colx[rowptr[d.z] + r.z] = s.z;
    colx[rowptr[d.w] + r.w] = s.w;
  }
}

// ---------------- aggregated_state = segment_sum(state[src], dst) ----------------
// wave per dst row; lanes 0-31 / 32-63 process interleaved edges (8 rows in flight)
__global__ __launch_bounds__(256) void agg2_k(const unsigned short* __restrict__ M,
                                              const int* __restrict__ rowptr,
                                              const int* __restrict__ colx,
                                              unsigned short* __restrict__ P, int N) {
  int wid = (blockIdx.x * 256 + threadIdx.x) >> 6;
  int lane = threadIdx.x & 63;
  if (wid >= N) return;
  int beg = rowptr[wid], end = rowptr[wid + 1];
  int half = lane >> 5, li = lane & 31;
  float a0 = 0.f, a1 = 0.f, a2 = 0.f, a3 = 0.f;
  int n = end - beg;
  int i = 0;
  for (; i + 8 <= n; i += 8) {
    int e = beg + i + half;
    int s0 = colx[e], s1 = colx[e + 2], s2 = colx[e + 4], s3 = colx[e + 6];
    uint2 v0 = *(const uint2*)(M + s0 * CC + li * 4);
    uint2 v1 = *(const uint2*)(M + s1 * CC + li * 4);
    uint2 v2 = *(const uint2*)(M + s2 * CC + li * 4);
    uint2 v3 = *(const uint2*)(M + s3 * CC + li * 4);
    a0 += bf2f(v0.x & 0xffffu); a1 += bf2f(v0.x >> 16); a2 += bf2f(v0.y & 0xffffu); a3 += bf2f(v0.y >> 16);
    a0 += bf2f(v1.x & 0xffffu); a1 += bf2f(v1.x >> 16); a2 += bf2f(v1.y & 0xffffu); a3 += bf2f(v1.y >> 16);
    a0 += bf2f(v2.x & 0xffffu); a1 += bf2f(v2.x >> 16); a2 += bf2f(v2.y & 0xffffu); a3 += bf2f(v2.y >> 16);
    a0 += bf2f(v3.x & 0xffffu); a1 += bf2f(v3.x >> 16); a2 += bf2f(v3.y & 0xffffu); a3 += bf2f(v3.y >> 16);
  }
  for (; i + 2 <= n; i += 2) {
    int e = beg + i + half;
    int s = colx[e];
    uint2 v = *(const uint2*)(M + s * CC + li * 4);
    a0 += bf2f(v.x & 0xffffu); a1 += bf2f(v.x >> 16); a2 += bf2f(v.y & 0xffffu); a3 += bf2f(v.y >> 16);
  }
  if (i < n && half == 0) {
    int s = colx[beg + i];
    uint2 v = *(const uint2*)(M + s * CC + li * 4);
    a0 += bf2f(v.x & 0xffffu); a1 += bf2f(v.x >> 16); a2 += bf2f(v.y & 0xffffu); a3 += bf2f(v.y >> 16);
  }
  a0 += __shfl_xor(a0, 32, 64);
  a1 += __shfl_xor(a1, 32, 64);
  a2 += __shfl_xor(a2, 32, 64);
  a3 += __shfl_xor(a3, 32, 64);
  if (half == 0) {
    uint2 o;
    o.x = (unsigned int)f2bf(a0) | ((unsigned int)f2bf(a1) << 16);
    o.y = (unsigned int)f2bf(a2) | ((unsigned int)f2bf(a3) << 16);
    *(uint2*)(P + wid * CC + li * 4) = o;
  }
}

// ---------------- fused gate GEMMs + GRU elementwise (weights in VGPRs) ----------------
// grid = 512: blockIdx&1 = column half (64 gate-cols), blockIdx>>1 = row group (stride 256)
__global__ __launch_bounds__(256, 2) void gru3_k(const unsigned short* __restrict__ Pb,
                                                 const unsigned short* __restrict__ Sb_in,
                                                 unsigned short* __restrict__ Sb_out,
                                                 const float* __restrict__ h_in,
                                                 float* __restrict__ h_out,
                                                 const unsigned short* __restrict__ Wcb,
                                                 const unsigned short* __restrict__ Whhb,
                                                 const float* __restrict__ bih,
                                                 const float* __restrict__ bhh) {
  __shared__ unsigned short sA[2][2][32][128];   // 32 KB: [buf][mat 0=agg 1=state]
  const int tid = threadIdx.x;
  const int half = blockIdx.x & 1;
  const int group = blockIdx.x >> 1;
  const int lane = tid & 63, w = tid >> 6;
  const int l15 = lane & 15, l4 = lane >> 4;

  const int c_loc = w * 16 + l15;
  const int cg = half * 64 + c_loc;

  // B fragments in registers: 6 panels x 4 k-steps x bf16x8 = 96 VGPR/lane.
  bf16x8 Breg[6][4];
  #pragma unroll
  for (int pi = 0; pi < 6; ++pi) {
    const unsigned short* Wm = (pi < 3) ? Wcb : Whhb;
    int p = (pi < 3) ? pi : pi - 3;
    const unsigned short* base = Wm + (p * 128 + cg) * 128 + l4 * 8;
    #pragma unroll
    for (int ks = 0; ks < 4; ++ks)
      Breg[pi][ks] = *(const bf16x8*)(base + ks * 32);
  }

  const float bir = bih[cg], biz = bih[cg + 128], bin_ = bih[cg + 256];
  const float bhr = bhh[cg], bhz = bhh[cg + 128], bhn = bhh[cg + 256];

  auto loadA = [&](int t, uint4* r) {
    int rowbase = t * 32;
    #pragma unroll
    for (int k = 0; k < 4; ++k) {
      int idx = k * 256 + tid;                 // 1024 chunks: [mat][row][ch]
      int mat = idx >> 9, j = idx & 511, row = j >> 4, ch = j & 15;
      int grow = rowbase + row;
      const unsigned short* srcp = mat ? Sb_in : Pb;
      r[k] = (grow < NN) ? *(const uint4*)(srcp + grow * 128 + ch * 8) : make_uint4(0, 0, 0, 0);
    }
  };
  auto writeA = [&](int buf, const uint4* r) {
    #pragma unroll
    for (int k = 0; k < 4; ++k) {
      int idx = k * 256 + tid;
      int mat = idx >> 9, j = idx & 511, row = j >> 4, ch = j & 15;
      *(uint4*)&sA[buf][mat][row][((ch ^ (row & 15)) * 8)] = r[k];
    }
  };

  uint4 pre[4];
  int t0 = group;
  loadA(t0, pre);
  writeA(0, pre);
  int cur = 0;
  for (int t = t0; t < NT; t += 256) {
    __syncthreads();
    int tn = t + 256;
    uint4 nxt[4];
    if (tn < NT) loadA(tn, nxt);

    f32x4 acc[6][2] = {};
    #pragma unroll
    for (int ks = 0; ks < 4; ++ks) {
      bf16x8 a[2][2];
      #pragma unroll
      for (int mat = 0; mat < 2; ++mat)
        #pragma unroll
        for (int rt = 0; rt < 2; ++rt) {
          int row = rt * 16 + l15;
          a[mat][rt] = *(const bf16x8*)&sA[cur][mat][row][(((ks * 4 + l4) ^ l15) * 8)];
        }
      #pragma unroll
      for (int pi = 0; pi < 6; ++pi) {
        int am = (pi < 3) ? 0 : 1;
        acc[pi][0] = __builtin_amdgcn_mfma_f32_16x16x32_bf16(a[am][0], Breg[pi][ks], acc[pi][0], 0, 0, 0);
        acc[pi][1] = __builtin_amdgcn_mfma_f32_16x16x32_bf16(a[am][1], Breg[pi][ks], acc[pi][1], 0, 0, 0);
      }
    }

    int rowbase = t * 32;
    #pragma unroll
    for (int rt = 0; rt < 2; ++rt)
      #pragma unroll
      for (int i = 0; i < 4; ++i) {
        int row = rowbase + rt * 16 + l4 * 4 + i;
        if (row < NN) {
          float gir = acc[0][rt][i] + bir;
          float giz = acc[1][rt][i] + biz;
          float gin = acc[2][rt][i] + bin_;
          float ghr = acc[3][rt][i] + bhr;
          float ghz = acc[4][rt][i] + bhz;
          float ghn = acc[5][rt][i] + bhn;
          float r = fsigmoid(gir + ghr);
          float z = fsigmoid(giz + ghz);
          float n = ftanh(gin + r * ghn);
          float h = h_in[row * 128 + cg];
          float o = n + z * (h - n);
          h_out[row * 128 + cg] = o;
          Sb_out[row * 128 + cg] = f2bf(o);
        }
      }
    if (tn < NT) writeA(cur ^ 1, nxt);
    cur ^= 1;
  }
}

extern "C" void kernel_launch(void* const* d_in, const int* in_sizes, int n_in,
                              void* d_out, int out_size, void* d_ws, size_t ws_size,
                              hipStream_t stream) {
  const float* x    = (const float*)d_in[0];
  const int*   ei   = (const int*)d_in[1];
  const float* Wlin = (const float*)d_in[2];
  const float* Wih  = (const float*)d_in[3];
  const float* Whh  = (const float*)d_in[4];
  const float* bih  = (const float*)d_in[5];
  const float* bhh  = (const float*)d_in[6];
  float* out = (float*)d_out;

  char* ws = (char*)d_ws;
  size_t off = 0;
  auto alloc = [&](size_t bytes) -> void* {
    void* p = ws + off;
    off += (bytes + 255) & ~(size_t)255;
    return p;
  };
  unsigned short* SbA  = (unsigned short*)alloc((size_t)NN * CC * 2);
  unsigned short* SbB  = (unsigned short*)alloc((size_t)NN * CC * 2);
  unsigned short* Prb  = (unsigned short*)alloc((size_t)NN * CC * 2);
  float*          Sf   = (float*)alloc((size_t)NN * CC * 4);
  unsigned short* Wcb  = (unsigned short*)alloc((size_t)3 * CC * CC * 2);
  unsigned short* Whhb = (unsigned short*)alloc((size_t)3 * CC * CC * 2);
  int* rowptr = (int*)alloc((size_t)(NN + 1) * 4);
  int* cnt    = (int*)alloc((size_t)NN * 4);
  int* rank   = (int*)alloc((size_t)EE * 4);
  int* colx   = (int*)alloc((size_t)EE * 4);
  int* bsum   = (int*)alloc(256 * 4);

  const int* srcI = ei;
  const int* dstI = ei + EE;

  cast_f2b_k<<<1024, 256, 0, stream>>>(x, SbA, NN * CC / 4);
  wprep_k<<<240, 256, 0, stream>>>(Wih, Wlin, Whh, Wcb, Whhb);

  zero_k<<<NBLK, 256, 0, stream>>>(cnt, NN);
  hist_k<<<(EE / 4 + 255) / 256, 256, 0, stream>>>(dstI, cnt, rank, EE / 4);
  scan1_k<<<NBLK, 256, 0, stream>>>(cnt, rowptr, bsum, NN);
  scan2_k<<<1, 256, 0, stream>>>(bsum, rowptr, NBLK);
  scan3_k<<<NBLK, 256, 0, stream>>>(rowptr, bsum, NN);
  fill_k<<<(EE / 4 + 255) / 256, 256, 0, stream>>>(srcI, dstI, rank, rowptr, colx, EE / 4);

  const int aggBlocks = (NN + 3) / 4;

  // step 1 (h = x, state = bf16(x))
  agg2_k<<<aggBlocks, 256, 0, stream>>>(SbA, rowptr, colx, Prb, NN);
  gru3_k<<<512, 256, 0, stream>>>(Prb, SbA, SbB, x, Sf, Wcb, Whhb, bih, bhh);
  // step 2
  agg2_k<<<aggBlocks, 256, 0, stream>>>(SbB, rowptr, colx, Prb, NN);
  gru3_k<<<512, 256, 0, stream>>>(Prb, SbB, SbA, Sf, Sf, Wcb, Whhb, bih, bhh);
  // step 3 (final state -> d_out)
  agg2_k<<<aggBlocks, 256, 0, stream>>>(SbA, rowptr, colx, Prb, NN);
  gru3_k<<<512, 256, 0, stream>>>(Prb, SbA, SbB, Sf, out, Wcb, Whhb, bih, bhh);
}

// Round 10
// 336.024 us; speedup vs baseline: 1.1960x; 1.0261x over previous
//
#include <hip/hip_runtime.h>

#define NN 50000
#define CC 128
#define EE 800000
#define NT 1563          // ceil(NN/32)
#define NBLK 196         // ceil(NN/256)

typedef short bf16x8 __attribute__((ext_vector_type(8)));
typedef float f32x4 __attribute__((ext_vector_type(4)));

__device__ __forceinline__ float bf2f(unsigned int u16) {
  union { unsigned int u; float f; } x; x.u = u16 << 16; return x.f;
}
__device__ __forceinline__ unsigned short f2bf(float f) {
  union { float f; unsigned int u; } x; x.f = f;
  unsigned int u = x.u;
  unsigned int r = (u + 0x7fffu + ((u >> 16) & 1u)) >> 16;
  return (unsigned short)r;
}
__device__ __forceinline__ float fsigmoid(float x) {
  return __fdividef(1.f, 1.f + __expf(-x));
}
__device__ __forceinline__ float ftanh(float x) {
  return 1.f - __fdividef(2.f, 1.f + __expf(2.f * x));
}

// ---------------- casts ----------------
__global__ void cast_f2b_k(const float* __restrict__ in, unsigned short* __restrict__ out, int n4) {
  int i = blockIdx.x * blockDim.x + threadIdx.x;
  int stride = gridDim.x * blockDim.x;
  for (; i < n4; i += stride) {
    float4 v = ((const float4*)in)[i];
    ushort4 o;
    o.x = f2bf(v.x); o.y = f2bf(v.y); o.z = f2bf(v.z); o.w = f2bf(v.w);
    ((ushort4*)out)[i] = o;
  }
}

// blocks 0-191: W_c = W_ih @ W_lin (384x128) fp32->bf16; blocks 192-239: cast Whh
__global__ __launch_bounds__(256) void wprep_k(const float* __restrict__ Wih,
                                               const float* __restrict__ Wlin,
                                               const float* __restrict__ Whh,
                                               unsigned short* __restrict__ Wcb,
                                               unsigned short* __restrict__ Whhb) {
  if (blockIdx.x < 192) {
    int gid = blockIdx.x * 256 + threadIdx.x;   // 49152 = 384*128
    int i = gid >> 7, j = gid & 127;
    float acc = 0.f;
    #pragma unroll 8
    for (int k = 0; k < 128; ++k)
      acc += Wih[i * 128 + k] * Wlin[k * 128 + j];
    Wcb[i * 128 + j] = f2bf(acc);
  } else {
    int i = (blockIdx.x - 192) * 256 + threadIdx.x;   // 12288 float4s
    float4 v = ((const float4*)Whh)[i];
    ushort4 o;
    o.x = f2bf(v.x); o.y = f2bf(v.y); o.z = f2bf(v.z); o.w = f2bf(v.w);
    ((ushort4*)Whhb)[i] = o;
  }
}

__global__ void zero_k(int* __restrict__ p, int n) {
  int i = blockIdx.x * blockDim.x + threadIdx.x;
  if (i < n) p[i] = 0;
}

// ---------------- CSR build ----------------
// 1 edge per thread: maximize waves/outstanding atomics (latency-bound kernel)
__global__ void hist_k(const int* __restrict__ dst, int* __restrict__ cnt,
                       int* __restrict__ rank, int n) {
  int i = blockIdx.x * blockDim.x + threadIdx.x;
  if (i < n) rank[i] = atomicAdd(&cnt[dst[i]], 1);
}

__global__ __launch_bounds__(256) void scan1_k(const int* __restrict__ cnt,
                                               int* __restrict__ rowptr,
                                               int* __restrict__ bsum, int N) {
  __shared__ int wtot[4];
  int tid = threadIdx.x, lane = tid & 63, w = tid >> 6;
  int i = blockIdx.x * 256 + tid;
  int v = (i < N) ? cnt[i] : 0;
  int x = v;
  #pragma unroll
  for (int off = 1; off < 64; off <<= 1) {
    int t = __shfl_up(x, off, 64);
    if (lane >= off) x += t;
  }
  if (lane == 63) wtot[w] = x;
  __syncthreads();
  int woff = 0;
  for (int j = 0; j < w; ++j) woff += wtot[j];
  int excl = x - v + woff;
  if (i < N) rowptr[i] = excl;
  if (tid == 255) bsum[blockIdx.x] = excl + v;
}

__global__ __launch_bounds__(256) void scan2_k(int* __restrict__ bsum, int* __restrict__ rowptr, int NB) {
  __shared__ int wtot[4];
  int tid = threadIdx.x, lane = tid & 63, w = tid >> 6;
  int v = (tid < NB) ? bsum[tid] : 0;
  int x = v;
  #pragma unroll
  for (int off = 1; off < 64; off <<= 1) {
    int t = __shfl_up(x, off, 64);
    if (lane >= off) x += t;
  }
  if (lane == 63) wtot[w] = x;
  __syncthreads();
  int woff = 0;
  for (int j = 0; j < w; ++j) woff += wtot[j];
  int excl = x - v + woff;
  if (tid < NB) bsum[tid] = excl;
  if (tid == 255) rowptr[NN] = excl + v;
}

__global__ void scan3_k(int* __restrict__ rowptr, const int* __restrict__ bsum, int N) {
  int i = blockIdx.x * 256 + threadIdx.x;
  if (i < N) rowptr[i] = rowptr[i] + bsum[i >> 8];
}

// atomic-free fill: pos = rowptr[dst] + rank  (plain scatter stores, fully pipelined)
__global__ void fill_k(const int* __restrict__ src, const int* __restrict__ dst,
                       const int* __restrict__ rank, const int* __restrict__ rowptr,
                       int* __restrict__ colx, int n4) {
  int i = blockIdx.x * blockDim.x + threadIdx.x;
  if (i < n4) {
    int4 s = ((const int4*)src)[i];
    int4 d = ((const int4*)dst)[i];
    int4 r = ((const int4*)rank)[i];
    colx[rowptr[d.x] + r.x] = s.x;
    colx[rowptr[d.y] + r.y] = s.y;
    colx[rowptr[d.z] + r.z] = s.z;
    colx[rowptr[d.w] + r.w] = s.w;
  }
}

// ---------------- aggregated_state = segment_sum(state[src], dst) ----------------
// wave per dst row; lanes 0-31 / 32-63 process interleaved edges (8 rows in flight)
__global__ __launch_bounds__(256) void agg2_k(const unsigned short* __restrict__ M,
                                              const int* __restrict__ rowptr,
                                              const int* __restrict__ colx,
                                              unsigned short* __restrict__ P, int N) {
  int wid = (blockIdx.x * 256 + threadIdx.x) >> 6;
  int lane = threadIdx.x & 63;
  if (wid >= N) return;
  int beg = rowptr[wid], end = rowptr[wid + 1];
  int half = lane >> 5, li = lane & 31;
  float a0 = 0.f, a1 = 0.f, a2 = 0.f, a3 = 0.f;
  int n = end - beg;
  int i = 0;
  for (; i + 8 <= n; i += 8) {
    int e = beg + i + half;
    int s0 = colx[e], s1 = colx[e + 2], s2 = colx[e + 4], s3 = colx[e + 6];
    uint2 v0 = *(const uint2*)(M + s0 * CC + li * 4);
    uint2 v1 = *(const uint2*)(M + s1 * CC + li * 4);
    uint2 v2 = *(const uint2*)(M + s2 * CC + li * 4);
    uint2 v3 = *(const uint2*)(M + s3 * CC + li * 4);
    a0 += bf2f(v0.x & 0xffffu); a1 += bf2f(v0.x >> 16); a2 += bf2f(v0.y & 0xffffu); a3 += bf2f(v0.y >> 16);
    a0 += bf2f(v1.x & 0xffffu); a1 += bf2f(v1.x >> 16); a2 += bf2f(v1.y & 0xffffu); a3 += bf2f(v1.y >> 16);
    a0 += bf2f(v2.x & 0xffffu); a1 += bf2f(v2.x >> 16); a2 += bf2f(v2.y & 0xffffu); a3 += bf2f(v2.y >> 16);
    a0 += bf2f(v3.x & 0xffffu); a1 += bf2f(v3.x >> 16); a2 += bf2f(v3.y & 0xffffu); a3 += bf2f(v3.y >> 16);
  }
  for (; i + 2 <= n; i += 2) {
    int e = beg + i + half;
    int s = colx[e];
    uint2 v = *(const uint2*)(M + s * CC + li * 4);
    a0 += bf2f(v.x & 0xffffu); a1 += bf2f(v.x >> 16); a2 += bf2f(v.y & 0xffffu); a3 += bf2f(v.y >> 16);
  }
  if (i < n && half == 0) {
    int s = colx[beg + i];
    uint2 v = *(const uint2*)(M + s * CC + li * 4);
    a0 += bf2f(v.x & 0xffffu); a1 += bf2f(v.x >> 16); a2 += bf2f(v.y & 0xffffu); a3 += bf2f(v.y >> 16);
  }
  a0 += __shfl_xor(a0, 32, 64);
  a1 += __shfl_xor(a1, 32, 64);
  a2 += __shfl_xor(a2, 32, 64);
  a3 += __shfl_xor(a3, 32, 64);
  if (half == 0) {
    uint2 o;
    o.x = (unsigned int)f2bf(a0) | ((unsigned int)f2bf(a1) << 16);
    o.y = (unsigned int)f2bf(a2) | ((unsigned int)f2bf(a3) << 16);
    *(uint2*)(P + wid * CC + li * 4) = o;
  }
}

// ---------------- fused gate GEMMs + GRU elementwise ----------------
// 512 threads = 8 waves covering all 128 gate-cols; one block per row-group
// (A-tile fetched ONCE per tile). h read as bf16 from the staged state tile in
// LDS (no fp32 h stream). fout!=null (step 3): write fp32 out, skip Sb write.
__global__ __launch_bounds__(512, 2) void gru4_k(const unsigned short* __restrict__ Pb,
                                                 const unsigned short* __restrict__ Sb_in,
                                                 unsigned short* __restrict__ Sb_out,
                                                 float* __restrict__ fout,
                                                 const unsigned short* __restrict__ Wcb,
                                                 const unsigned short* __restrict__ Whhb,
                                                 const float* __restrict__ bih,
                                                 const float* __restrict__ bhh) {
  __shared__ unsigned short sA[2][2][32][128];   // 32 KB: [buf][mat 0=agg 1=state]
  const int tid = threadIdx.x;
  const int lane = tid & 63, w = tid >> 6;       // w in [0,8)
  const int l15 = lane & 15, l4 = lane >> 4;

  const int cg = w * 16 + l15;                   // all 128 gate-cols covered

  // B fragments in registers: 6 panels x 4 k-steps x bf16x8 = 96 VGPR/lane.
  bf16x8 Breg[6][4];
  #pragma unroll
  for (int pi = 0; pi < 6; ++pi) {
    const unsigned short* Wm = (pi < 3) ? Wcb : Whhb;
    int p = (pi < 3) ? pi : pi - 3;
    const unsigned short* base = Wm + (p * 128 + cg) * 128 + l4 * 8;
    #pragma unroll
    for (int ks = 0; ks < 4; ++ks)
      Breg[pi][ks] = *(const bf16x8*)(base + ks * 32);
  }

  const float bir = bih[cg], biz = bih[cg + 128], bin_ = bih[cg + 256];
  const float bhr = bhh[cg], bhz = bhh[cg + 128], bhn = bhh[cg + 256];

  auto loadA = [&](int t, uint4* r) {
    int rowbase = t * 32;
    #pragma unroll
    for (int k = 0; k < 2; ++k) {
      int idx = k * 512 + tid;                 // 1024 chunks: [mat][row][ch]
      int mat = idx >> 9, j = idx & 511, row = j >> 4, ch = j & 15;
      int grow = rowbase + row;
      const unsigned short* srcp = mat ? Sb_in : Pb;
      r[k] = (grow < NN) ? *(const uint4*)(srcp + grow * 128 + ch * 8) : make_uint4(0, 0, 0, 0);
    }
  };
  auto writeA = [&](int buf, const uint4* r) {
    #pragma unroll
    for (int k = 0; k < 2; ++k) {
      int idx = k * 512 + tid;
      int mat = idx >> 9, j = idx & 511, row = j >> 4, ch = j & 15;
      *(uint4*)&sA[buf][mat][row][((ch ^ (row & 15)) * 8)] = r[k];
    }
  };

  uint4 pre[2];
  int t0 = blockIdx.x;
  loadA(t0, pre);
  writeA(0, pre);
  int cur = 0;
  for (int t = t0; t < NT; t += 256) {
    __syncthreads();
    int tn = t + 256;
    uint4 nxt[2];
    if (tn < NT) loadA(tn, nxt);

    f32x4 acc[6][2] = {};
    #pragma unroll
    for (int ks = 0; ks < 4; ++ks) {
      bf16x8 a[2][2];
      #pragma unroll
      for (int mat = 0; mat < 2; ++mat)
        #pragma unroll
        for (int rt = 0; rt < 2; ++rt) {
          int row = rt * 16 + l15;
          a[mat][rt] = *(const bf16x8*)&sA[cur][mat][row][(((ks * 4 + l4) ^ l15) * 8)];
        }
      #pragma unroll
      for (int pi = 0; pi < 6; ++pi) {
        int am = (pi < 3) ? 0 : 1;
        acc[pi][0] = __builtin_amdgcn_mfma_f32_16x16x32_bf16(a[am][0], Breg[pi][ks], acc[pi][0], 0, 0, 0);
        acc[pi][1] = __builtin_amdgcn_mfma_f32_16x16x32_bf16(a[am][1], Breg[pi][ks], acc[pi][1], 0, 0, 0);
      }
    }

    int rowbase = t * 32;
    #pragma unroll
    for (int rt = 0; rt < 2; ++rt)
      #pragma unroll
      for (int i = 0; i < 4; ++i) {
        int row_loc = rt * 16 + l4 * 4 + i;
        int row = rowbase + row_loc;
        if (row < NN) {
          float gir = acc[0][rt][i] + bir;
          float giz = acc[1][rt][i] + biz;
          float gin = acc[2][rt][i] + bin_;
          float ghr = acc[3][rt][i] + bhr;
          float ghz = acc[4][rt][i] + bhz;
          float ghn = acc[5][rt][i] + bhn;
          float r = fsigmoid(gir + ghr);
          float z = fsigmoid(giz + ghz);
          float n = ftanh(gin + r * ghn);
          // h from the staged bf16 state tile in LDS (swizzled layout)
          float h = bf2f((unsigned int)sA[cur][1][row_loc][(((cg >> 3) ^ (row_loc & 15)) << 3) + (cg & 7)]);
          float o = n + z * (h - n);
          if (fout) fout[row * 128 + cg] = o;
          else      Sb_out[row * 128 + cg] = f2bf(o);
        }
      }
    if (tn < NT) writeA(cur ^ 1, nxt);
    cur ^= 1;
  }
}

extern "C" void kernel_launch(void* const* d_in, const int* in_sizes, int n_in,
                              void* d_out, int out_size, void* d_ws, size_t ws_size,
                              hipStream_t stream) {
  const float* x    = (const float*)d_in[0];
  const int*   ei   = (const int*)d_in[1];
  const float* Wlin = (const float*)d_in[2];
  const float* Wih  = (const float*)d_in[3];
  const float* Whh  = (const float*)d_in[4];
  const float* bih  = (const float*)d_in[5];
  const float* bhh  = (const float*)d_in[6];
  float* out = (float*)d_out;

  char* ws = (char*)d_ws;
  size_t off = 0;
  auto alloc = [&](size_t bytes) -> void* {
    void* p = ws + off;
    off += (bytes + 255) & ~(size_t)255;
    return p;
  };
  unsigned short* SbA  = (unsigned short*)alloc((size_t)NN * CC * 2);
  unsigned short* SbB  = (unsigned short*)alloc((size_t)NN * CC * 2);
  unsigned short* Prb  = (unsigned short*)alloc((size_t)NN * CC * 2);
  unsigned short* Wcb  = (unsigned short*)alloc((size_t)3 * CC * CC * 2);
  unsigned short* Whhb = (unsigned short*)alloc((size_t)3 * CC * CC * 2);
  int* rowptr = (int*)alloc((size_t)(NN + 1) * 4);
  int* cnt    = (int*)alloc((size_t)NN * 4);
  int* rank   = (int*)alloc((size_t)EE * 4);
  int* colx   = (int*)alloc((size_t)EE * 4);
  int* bsum   = (int*)alloc(256 * 4);

  const int* srcI = ei;
  const int* dstI = ei + EE;

  cast_f2b_k<<<1024, 256, 0, stream>>>(x, SbA, NN * CC / 4);
  wprep_k<<<240, 256, 0, stream>>>(Wih, Wlin, Whh, Wcb, Whhb);

  zero_k<<<NBLK, 256, 0, stream>>>(cnt, NN);
  hist_k<<<EE / 256, 256, 0, stream>>>(dstI, cnt, rank, EE);
  scan1_k<<<NBLK, 256, 0, stream>>>(cnt, rowptr, bsum, NN);
  scan2_k<<<1, 256, 0, stream>>>(bsum, rowptr, NBLK);
  scan3_k<<<NBLK, 256, 0, stream>>>(rowptr, bsum, NN);
  fill_k<<<(EE / 4 + 255) / 256, 256, 0, stream>>>(srcI, dstI, rank, rowptr, colx, EE / 4);

  const int aggBlocks = (NN + 3) / 4;

  // step 1 (h = bf16(x) = SbA, read from LDS inside gru4)
  agg2_k<<<aggBlocks, 256, 0, stream>>>(SbA, rowptr, colx, Prb, NN);
  gru4_k<<<256, 512, 0, stream>>>(Prb, SbA, SbB, nullptr, Wcb, Whhb, bih, bhh);
  // step 2
  agg2_k<<<aggBlocks, 256, 0, stream>>>(SbB, rowptr, colx, Prb, NN);
  gru4_k<<<256, 512, 0, stream>>>(Prb, SbB, SbA, nullptr, Wcb, Whhb, bih, bhh);
  // step 3 (final state -> d_out, fp32)
  agg2_k<<<aggBlocks, 256, 0, stream>>>(SbA, rowptr, colx, Prb, NN);
  gru4_k<<<256, 512, 0, stream>>>(Prb, SbA, SbB, out, Wcb, Whhb, bih, bhh);
}

// Round 12
// 329.396 us; speedup vs baseline: 1.2201x; 1.0201x over previous
//
#include <hip/hip_runtime.h>

#define NN 50000
#define CC 128
#define EE 800000
#define NT 1563          // ceil(NN/32)
#define NBLK 196         // ceil(NN/256)

typedef short bf16x8 __attribute__((ext_vector_type(8)));
typedef float f32x4 __attribute__((ext_vector_type(4)));

__device__ __forceinline__ float bf2f(unsigned int u16) {
  union { unsigned int u; float f; } x; x.u = u16 << 16; return x.f;
}
__device__ __forceinline__ unsigned short f2bf(float f) {
  union { float f; unsigned int u; } x; x.f = f;
  unsigned int u = x.u;
  unsigned int r = (u + 0x7fffu + ((u >> 16) & 1u)) >> 16;
  return (unsigned short)r;
}
__device__ __forceinline__ float fsigmoid(float x) {
  return __fdividef(1.f, 1.f + __expf(-x));
}
__device__ __forceinline__ float ftanh(float x) {
  return 1.f - __fdividef(2.f, 1.f + __expf(2.f * x));
}

// ---------------- casts ----------------
__global__ void cast_f2b_k(const float* __restrict__ in, unsigned short* __restrict__ out, int n4) {
  int i = blockIdx.x * blockDim.x + threadIdx.x;
  int stride = gridDim.x * blockDim.x;
  for (; i < n4; i += stride) {
    float4 v = ((const float4*)in)[i];
    ushort4 o;
    o.x = f2bf(v.x); o.y = f2bf(v.y); o.z = f2bf(v.z); o.w = f2bf(v.w);
    ((ushort4*)out)[i] = o;
  }
}

// blocks 0-191: W_c = W_ih @ W_lin (384x128) fp32->bf16; blocks 192-239: cast Whh
__global__ __launch_bounds__(256) void wprep_k(const float* __restrict__ Wih,
                                               const float* __restrict__ Wlin,
                                               const float* __restrict__ Whh,
                                               unsigned short* __restrict__ Wcb,
                                               unsigned short* __restrict__ Whhb) {
  if (blockIdx.x < 192) {
    int gid = blockIdx.x * 256 + threadIdx.x;   // 49152 = 384*128
    int i = gid >> 7, j = gid & 127;
    float acc = 0.f;
    #pragma unroll 8
    for (int k = 0; k < 128; ++k)
      acc += Wih[i * 128 + k] * Wlin[k * 128 + j];
    Wcb[i * 128 + j] = f2bf(acc);
  } else {
    int i = (blockIdx.x - 192) * 256 + threadIdx.x;   // 12288 float4s
    float4 v = ((const float4*)Whh)[i];
    ushort4 o;
    o.x = f2bf(v.x); o.y = f2bf(v.y); o.z = f2bf(v.z); o.w = f2bf(v.w);
    ((ushort4*)Whhb)[i] = o;
  }
}

__global__ void zero_k(int* __restrict__ p, int n) {
  int i = blockIdx.x * blockDim.x + threadIdx.x;
  if (i < n) p[i] = 0;
}

// ---------------- CSR build ----------------
// XCD-replicated histogram: replica = blockIdx&7 (round-robin block->XCD heuristic)
// keeps each replica's atomic lines in one XCD's L2 (no cross-XCD ping-pong).
__global__ void hist_k(const int* __restrict__ dst, int* __restrict__ cntrep,
                       int* __restrict__ rank, int n) {
  int i = blockIdx.x * blockDim.x + threadIdx.x;
  int rep = blockIdx.x & 7;
  if (i < n) rank[i] = atomicAdd(&cntrep[rep * NN + dst[i]], 1);
}

// per-dst: exclusive prefix over the 8 replicas (offsets back into cntrep),
// total feeds the block-level scan.
__global__ __launch_bounds__(256) void scan1_k(int* __restrict__ cntrep,
                                               int* __restrict__ rowptr,
                                               int* __restrict__ bsum, int N) {
  __shared__ int wtot[4];
  int tid = threadIdx.x, lane = tid & 63, w = tid >> 6;
  int i = blockIdx.x * 256 + tid;
  int v = 0;
  if (i < N) {
    int s = 0;
    #pragma unroll
    for (int r = 0; r < 8; ++r) {
      int c = cntrep[r * NN + i];
      cntrep[r * NN + i] = s;
      s += c;
    }
    v = s;
  }
  int x = v;
  #pragma unroll
  for (int off = 1; off < 64; off <<= 1) {
    int t = __shfl_up(x, off, 64);
    if (lane >= off) x += t;
  }
  if (lane == 63) wtot[w] = x;
  __syncthreads();
  int woff = 0;
  for (int j = 0; j < w; ++j) woff += wtot[j];
  int excl = x - v + woff;
  if (i < N) rowptr[i] = excl;
  if (tid == 255) bsum[blockIdx.x] = excl + v;
}

__global__ __launch_bounds__(256) void scan2_k(int* __restrict__ bsum, int* __restrict__ rowptr, int NB) {
  __shared__ int wtot[4];
  int tid = threadIdx.x, lane = tid & 63, w = tid >> 6;
  int v = (tid < NB) ? bsum[tid] : 0;
  int x = v;
  #pragma unroll
  for (int off = 1; off < 64; off <<= 1) {
    int t = __shfl_up(x, off, 64);
    if (lane >= off) x += t;
  }
  if (lane == 63) wtot[w] = x;
  __syncthreads();
  int woff = 0;
  for (int j = 0; j < w; ++j) woff += wtot[j];
  int excl = x - v + woff;
  if (tid < NB) bsum[tid] = excl;
  if (tid == 255) rowptr[NN] = excl + v;
}

__global__ void scan3_k(int* __restrict__ rowptr, const int* __restrict__ bsum, int N) {
  int i = blockIdx.x * 256 + threadIdx.x;
  if (i < N) rowptr[i] = rowptr[i] + bsum[i >> 8];
}

// atomic-free fill: pos = rowptr[dst] + repoff[rep][dst] + rank
// (rep of edge e = (e>>8)&7 == (thread>>6)&7 at 4 edges/thread)
__global__ void fill_k(const int* __restrict__ src, const int* __restrict__ dst,
                       const int* __restrict__ rank, const int* __restrict__ rowptr,
                       const int* __restrict__ cntrep, int* __restrict__ colx, int n4) {
  int i = blockIdx.x * blockDim.x + threadIdx.x;
  if (i < n4) {
    int4 s = ((const int4*)src)[i];
    int4 d = ((const int4*)dst)[i];
    int4 r = ((const int4*)rank)[i];
    int base = ((i >> 6) & 7) * NN;
    colx[rowptr[d.x] + cntrep[base + d.x] + r.x] = s.x;
    colx[rowptr[d.y] + cntrep[base + d.y] + r.y] = s.y;
    colx[rowptr[d.z] + cntrep[base + d.z] + r.z] = s.z;
    colx[rowptr[d.w] + cntrep[base + d.w] + r.w] = s.w;
  }
}

// ---------------- aggregated_state = segment_sum(state[src], dst) ----------------
// wave per dst row; 4 edge-slots x 16 lanes, uint4 loads (16 edges in flight)
__global__ __launch_bounds__(256) void agg3_k(const unsigned short* __restrict__ M,
                                              const int* __restrict__ rowptr,
                                              const int* __restrict__ colx,
                                              unsigned short* __restrict__ P, int N) {
  int wid = (blockIdx.x * 256 + threadIdx.x) >> 6;
  int lane = threadIdx.x & 63;
  if (wid >= N) return;
  int beg = rowptr[wid], end = rowptr[wid + 1];
  int slot = lane >> 4, li = lane & 15;
  float a0 = 0.f, a1 = 0.f, a2 = 0.f, a3 = 0.f, a4 = 0.f, a5 = 0.f, a6 = 0.f, a7 = 0.f;
  #define ACC(v) do { \
    a0 += bf2f((v).x & 0xffffu); a1 += bf2f((v).x >> 16); \
    a2 += bf2f((v).y & 0xffffu); a3 += bf2f((v).y >> 16); \
    a4 += bf2f((v).z & 0xffffu); a5 += bf2f((v).z >> 16); \
    a6 += bf2f((v).w & 0xffffu); a7 += bf2f((v).w >> 16); } while (0)
  int n = end - beg;
  int i = 0;
  for (; i + 16 <= n; i += 16) {
    int e = beg + i + slot;
    int s0 = colx[e], s1 = colx[e + 4], s2 = colx[e + 8], s3 = colx[e + 12];
    uint4 v0 = *(const uint4*)(M + s0 * CC + li * 8);
    uint4 v1 = *(const uint4*)(M + s1 * CC + li * 8);
    uint4 v2 = *(const uint4*)(M + s2 * CC + li * 8);
    uint4 v3 = *(const uint4*)(M + s3 * CC + li * 8);
    ACC(v0); ACC(v1); ACC(v2); ACC(v3);
  }
  for (; i + 4 <= n; i += 4) {
    int e = beg + i + slot;
    int s = colx[e];
    uint4 v = *(const uint4*)(M + s * CC + li * 8);
    ACC(v);
  }
  int rem = n - i;
  if (slot < rem) {
    int e = beg + i + slot;
    int s = colx[e];
    uint4 v = *(const uint4*)(M + s * CC + li * 8);
    ACC(v);
  }
  #undef ACC
  #pragma unroll
  for (int m = 16; m <= 32; m <<= 1) {
    a0 += __shfl_xor(a0, m, 64); a1 += __shfl_xor(a1, m, 64);
    a2 += __shfl_xor(a2, m, 64); a3 += __shfl_xor(a3, m, 64);
    a4 += __shfl_xor(a4, m, 64); a5 += __shfl_xor(a5, m, 64);
    a6 += __shfl_xor(a6, m, 64); a7 += __shfl_xor(a7, m, 64);
  }
  if (slot == 0) {
    uint4 o;
    o.x = (unsigned int)f2bf(a0) | ((unsigned int)f2bf(a1) << 16);
    o.y = (unsigned int)f2bf(a2) | ((unsigned int)f2bf(a3) << 16);
    o.z = (unsigned int)f2bf(a4) | ((unsigned int)f2bf(a5) << 16);
    o.w = (unsigned int)f2bf(a6) | ((unsigned int)f2bf(a7) << 16);
    *(uint4*)(P + wid * CC + li * 8) = o;
  }
}

// ---------------- fused gate GEMMs + GRU elementwise ----------------
// 512 threads = 8 waves covering all 128 gate-cols; one block per row-group
// (A-tile fetched ONCE per tile). h read as bf16 from the staged state tile in
// LDS (no fp32 h stream). fout!=null (step 3): write fp32 out, skip Sb write.
__global__ __launch_bounds__(512, 2) void gru4_k(const unsigned short* __restrict__ Pb,
                                                 const unsigned short* __restrict__ Sb_in,
                                                 unsigned short* __restrict__ Sb_out,
                                                 float* __restrict__ fout,
                                                 const unsigned short* __restrict__ Wcb,
                                                 const unsigned short* __restrict__ Whhb,
                                                 const float* __restrict__ bih,
                                                 const float* __restrict__ bhh) {
  __shared__ unsigned short sA[2][2][32][128];   // 32 KB: [buf][mat 0=agg 1=state]
  const int tid = threadIdx.x;
  const int lane = tid & 63, w = tid >> 6;       // w in [0,8)
  const int l15 = lane & 15, l4 = lane >> 4;

  const int cg = w * 16 + l15;                   // all 128 gate-cols covered

  // B fragments in registers: 6 panels x 4 k-steps x bf16x8 = 96 VGPR/lane.
  bf16x8 Breg[6][4];
  #pragma unroll
  for (int pi = 0; pi < 6; ++pi) {
    const unsigned short* Wm = (pi < 3) ? Wcb : Whhb;
    int p = (pi < 3) ? pi : pi - 3;
    const unsigned short* base = Wm + (p * 128 + cg) * 128 + l4 * 8;
    #pragma unroll
    for (int ks = 0; ks < 4; ++ks)
      Breg[pi][ks] = *(const bf16x8*)(base + ks * 32);
  }

  const float bir = bih[cg], biz = bih[cg + 128], bin_ = bih[cg + 256];
  const float bhr = bhh[cg], bhz = bhh[cg + 128], bhn = bhh[cg + 256];

  auto loadA = [&](int t, uint4* r) {
    int rowbase = t * 32;
    #pragma unroll
    for (int k = 0; k < 2; ++k) {
      int idx = k * 512 + tid;                 // 1024 chunks: [mat][row][ch]
      int mat = idx >> 9, j = idx & 511, row = j >> 4, ch = j & 15;
      int grow = rowbase + row;
      const unsigned short* srcp = mat ? Sb_in : Pb;
      r[k] = (grow < NN) ? *(const uint4*)(srcp + grow * 128 + ch * 8) : make_uint4(0, 0, 0, 0);
    }
  };
  auto writeA = [&](int buf, const uint4* r) {
    #pragma unroll
    for (int k = 0; k < 2; ++k) {
      int idx = k * 512 + tid;
      int mat = idx >> 9, j = idx & 511, row = j >> 4, ch = j & 15;
      *(uint4*)&sA[buf][mat][row][((ch ^ (row & 15)) * 8)] = r[k];
    }
  };

  uint4 pre[2];
  int t0 = blockIdx.x;
  loadA(t0, pre);
  writeA(0, pre);
  int cur = 0;
  for (int t = t0; t < NT; t += 256) {
    __syncthreads();
    int tn = t + 256;
    uint4 nxt[2];
    if (tn < NT) loadA(tn, nxt);

    f32x4 acc[6][2] = {};
    #pragma unroll
    for (int ks = 0; ks < 4; ++ks) {
      bf16x8 a[2][2];
      #pragma unroll
      for (int mat = 0; mat < 2; ++mat)
        #pragma unroll
        for (int rt = 0; rt < 2; ++rt) {
          int row = rt * 16 + l15;
          a[mat][rt] = *(const bf16x8*)&sA[cur][mat][row][(((ks * 4 + l4) ^ l15) * 8)];
        }
      #pragma unroll
      for (int pi = 0; pi < 6; ++pi) {
        int am = (pi < 3) ? 0 : 1;
        acc[pi][0] = __builtin_amdgcn_mfma_f32_16x16x32_bf16(a[am][0], Breg[pi][ks], acc[pi][0], 0, 0, 0);
        acc[pi][1] = __builtin_amdgcn_mfma_f32_16x16x32_bf16(a[am][1], Breg[pi][ks], acc[pi][1], 0, 0, 0);
      }
    }

    int rowbase = t * 32;
    #pragma unroll
    for (int rt = 0; rt < 2; ++rt)
      #pragma unroll
      for (int i = 0; i < 4; ++i) {
        int row_loc = rt * 16 + l4 * 4 + i;
        int row = rowbase + row_loc;
        if (row < NN) {
          float gir = acc[0][rt][i] + bir;
          float giz = acc[1][rt][i] + biz;
          float gin = acc[2][rt][i] + bin_;
          float ghr = acc[3][rt][i] + bhr;
          float ghz = acc[4][rt][i] + bhz;
          float ghn = acc[5][rt][i] + bhn;
          float r = fsigmoid(gir + ghr);
          float z = fsigmoid(giz + ghz);
          float n = ftanh(gin + r * ghn);
          // h from the staged bf16 state tile in LDS (swizzled layout)
          float h = bf2f((unsigned int)sA[cur][1][row_loc][(((cg >> 3) ^ (row_loc & 15)) << 3) + (cg & 7)]);
          float o = n + z * (h - n);
          if (fout) fout[row * 128 + cg] = o;
          else      Sb_out[row * 128 + cg] = f2bf(o);
        }
      }
    if (tn < NT) writeA(cur ^ 1, nxt);
    cur ^= 1;
  }
}

extern "C" void kernel_launch(void* const* d_in, const int* in_sizes, int n_in,
                              void* d_out, int out_size, void* d_ws, size_t ws_size,
                              hipStream_t stream) {
  const float* x    = (const float*)d_in[0];
  const int*   ei   = (const int*)d_in[1];
  const float* Wlin = (const float*)d_in[2];
  const float* Wih  = (const float*)d_in[3];
  const float* Whh  = (const float*)d_in[4];
  const float* bih  = (const float*)d_in[5];
  const float* bhh  = (const float*)d_in[6];
  float* out = (float*)d_out;

  char* ws = (char*)d_ws;
  size_t off = 0;
  auto alloc = [&](size_t bytes) -> void* {
    void* p = ws + off;
    off += (bytes + 255) & ~(size_t)255;
    return p;
  };
  unsigned short* SbA  = (unsigned short*)alloc((size_t)NN * CC * 2);
  unsigned short* SbB  = (unsigned short*)alloc((size_t)NN * CC * 2);
  unsigned short* Prb  = (unsigned short*)alloc((size_t)NN * CC * 2);
  unsigned short* Wcb  = (unsigned short*)alloc((size_t)3 * CC * CC * 2);
  unsigned short* Whhb = (unsigned short*)alloc((size_t)3 * CC * CC * 2);
  int* rowptr = (int*)alloc((size_t)(NN + 1) * 4);
  int* cntrep = (int*)alloc((size_t)8 * NN * 4);
  int* rank   = (int*)alloc((size_t)EE * 4);
  int* colx   = (int*)alloc((size_t)EE * 4);
  int* bsum   = (int*)alloc(256 * 4);

  const int* srcI = ei;
  const int* dstI = ei + EE;

  cast_f2b_k<<<1024, 256, 0, stream>>>(x, SbA, NN * CC / 4);
  wprep_k<<<240, 256, 0, stream>>>(Wih, Wlin, Whh, Wcb, Whhb);

  zero_k<<<(8 * NN + 255) / 256, 256, 0, stream>>>(cntrep, 8 * NN);
  hist_k<<<EE / 256, 256, 0, stream>>>(dstI, cntrep, rank, EE);
  scan1_k<<<NBLK, 256, 0, stream>>>(cntrep, rowptr, bsum, NN);
  scan2_k<<<1, 256, 0, stream>>>(bsum, rowptr, NBLK);
  scan3_k<<<NBLK, 256, 0, stream>>>(rowptr, bsum, NN);
  fill_k<<<(EE / 4 + 255) / 256, 256, 0, stream>>>(srcI, dstI, rank, rowptr, cntrep, colx, EE / 4);

  const int aggBlocks = (NN + 3) / 4;

  // step 1 (h = bf16(x) = SbA, read from LDS inside gru4)
  agg3_k<<<aggBlocks, 256, 0, stream>>>(SbA, rowptr, colx, Prb, NN);
  gru4_k<<<256, 512, 0, stream>>>(Prb, SbA, SbB, nullptr, Wcb, Whhb, bih, bhh);
  // step 2
  agg3_k<<<aggBlocks, 256, 0, stream>>>(SbB, rowptr, colx, Prb, NN);
  gru4_k<<<256, 512, 0, stream>>>(Prb, SbB, SbA, nullptr, Wcb, Whhb, bih, bhh);
  // step 3 (final state -> d_out, fp32)
  agg3_k<<<aggBlocks, 256, 0, stream>>>(SbA, rowptr, colx, Prb, NN);
  gru4_k<<<256, 512, 0, stream>>>(Prb, SbA, SbB, out, Wcb, Whhb, bih, bhh);
}